// Round 9
// baseline (241.128 us; speedup 1.0000x reference)
//
#include <hip/hip_runtime.h>

#define B_    2
#define N_    2304
#define C_    768
#define HEADS 12
#define D_    64
#define F3    2304
#define M_    (B_*N_)        // 4608
#define SPLITS 2
#define KSPAN (N_/SPLITS)    // 1152
// SCALE(0.125) * log2(e) folded into Q at qkv epilogue:
#define QSCALE 0.18033688011112042f

typedef __attribute__((ext_vector_type(8)))  short bfrag;    // 8 x bf16 (4 VGPR)
typedef __attribute__((ext_vector_type(4)))  float ffrag;    // 16x16 acc
typedef __attribute__((ext_vector_type(16))) float ffrag16;  // 32x32 acc
typedef __attribute__((ext_vector_type(4)))  unsigned ufrag; // 4 x b32 = 8 bf16

__device__ __forceinline__ short f2bf(float f) {
    unsigned u = __float_as_uint(f);
    u += 0x7fff + ((u >> 16) & 1);          // RNE
    return (short)(u >> 16);
}

__device__ __forceinline__ void gl2lds16(const void* g, void* l) {
    __builtin_amdgcn_global_load_lds(
        (const __attribute__((address_space(1))) void*)g,
        (__attribute__((address_space(3))) void*)l, 16, 0, 0);
}

// trunc-pack two fp32 -> (bf16(a) low | bf16(b) high) in ONE v_perm_b32.
// bias-safe: numerator (PV) and denominator (ones-MFMA) consume the same
// truncated fragments -> common bias cancels in the ratio.
__device__ __forceinline__ unsigned pktrunc(float a, float b) {
    return __builtin_amdgcn_perm(__float_as_uint(a), __float_as_uint(b),
                                 0x03020706u);
}

// ---------------------------------------------------------------------------
// Fused fp32 -> bf16 cast of x, qkv_w, proj_w (dsts contiguous in ws).
// ---------------------------------------------------------------------------
__global__ __launch_bounds__(256) void cast_all(const float* __restrict__ x,
                                                const float* __restrict__ qw,
                                                const float* __restrict__ pw,
                                                short* __restrict__ dst) {
    const int nx4 = (M_*C_)/4, nq4 = (F3*C_)/4, np4 = (C_*C_)/4;
    int i = blockIdx.x * 256 + threadIdx.x;
    if (i >= nx4 + nq4 + np4) return;
    const float* src; int off;
    if (i < nx4)            { src = x;  off = i; }
    else if (i < nx4 + nq4) { src = qw; off = i - nx4; }
    else                    { src = pw; off = i - nx4 - nq4; }
    float4 v = ((const float4*)src)[off];
    short4 o;
    o.x = f2bf(v.x); o.y = f2bf(v.y); o.z = f2bf(v.z); o.w = f2bf(v.w);
    ((short4*)dst)[i] = o;
}

// ---------------------------------------------------------------------------
// QKV GEMM: qkv[m][f] = sum_c x[m][c]*w[f][c]  (NT).  BK=64, XOR-swizzled
// staging (slot = chunk ^ (row&7)); 12 k-iters, 32 MFMA/iter.
// Q stored pre-scaled by SCALE*log2e; V stored transposed [bh,d,n].
// ---------------------------------------------------------------------------
__global__ __launch_bounds__(256) void qkv_gemm(const short* __restrict__ xb,
                                                const short* __restrict__ wb,
                                                short* __restrict__ Qb,
                                                short* __restrict__ Kb,
                                                short* __restrict__ Vtb) {
    __shared__ short As[128*64];
    __shared__ short Bs[128*64];
    const int t = threadIdx.x;
    const int w = t >> 6, lane = t & 63;
    const int quad = lane >> 4, l15 = lane & 15;
    const int wr = w >> 1, wc = w & 1;
    const int m0 = blockIdx.y * 128, f0 = blockIdx.x * 128;
    const int lrow = lane >> 3;            // row within 8-row segment
    const int lc   = (lane & 7) ^ lrow;    // swizzled source chunk
    const int r7   = l15 & 7;              // frag-row swizzle key

    ffrag acc[4][4] = {};

    for (int k0 = 0; k0 < C_; k0 += 64) {
        __syncthreads();
        #pragma unroll
        for (int r = 0; r < 4; ++r) {
            int seg = r*4 + w;                 // 16 segments of 8 rows
            int row = seg*8 + lrow;
            gl2lds16(xb + (size_t)(m0+row)*C_ + k0 + lc*8, As + seg*512);
            gl2lds16(wb + (size_t)(f0+row)*C_ + k0 + lc*8, Bs + seg*512);
        }
        __syncthreads();
        #pragma unroll
        for (int s = 0; s < 2; ++s) {
            bfrag af[4], bf[4];
            int slot = (s*4 + quad) ^ r7;
            #pragma unroll
            for (int i = 0; i < 4; ++i)
                af[i] = *(const bfrag*)(As + (wr*64 + i*16 + l15)*64 + slot*8);
            #pragma unroll
            for (int j = 0; j < 4; ++j)
                bf[j] = *(const bfrag*)(Bs + (wc*64 + j*16 + l15)*64 + slot*8);
            #pragma unroll
            for (int i = 0; i < 4; ++i)
                #pragma unroll
                for (int j = 0; j < 4; ++j)
                    acc[i][j] = __builtin_amdgcn_mfma_f32_16x16x32_bf16(af[i], bf[j], acc[i][j], 0, 0, 0);
        }
    }

    const int b   = m0 / N_;
    const int seg = f0 + wc*64;
    const int which = seg / C_;                  // 0=Q 1=K 2=V
    const int head  = (seg - which*C_) >> 6;
    const int bh    = b*HEADS + head;
    const int nbase = (m0 - b*N_) + wr*64 + quad*4;

    if (which == 0) {
        #pragma unroll
        for (int i = 0; i < 4; ++i) {
            int n0 = nbase + i*16;
            #pragma unroll
            for (int j = 0; j < 4; ++j) {
                int d = j*16 + l15;
                #pragma unroll
                for (int r = 0; r < 4; ++r)
                    Qb[((size_t)bh*N_ + n0 + r)*D_ + d] = f2bf(acc[i][j][r] * QSCALE);
            }
        }
    } else if (which == 1) {
        #pragma unroll
        for (int i = 0; i < 4; ++i) {
            int n0 = nbase + i*16;
            #pragma unroll
            for (int j = 0; j < 4; ++j) {
                int d = j*16 + l15;
                #pragma unroll
                for (int r = 0; r < 4; ++r)
                    Kb[((size_t)bh*N_ + n0 + r)*D_ + d] = f2bf(acc[i][j][r]);
            }
        }
    } else {
        #pragma unroll
        for (int i = 0; i < 4; ++i) {
            int n0 = nbase + i*16;
            #pragma unroll
            for (int j = 0; j < 4; ++j) {
                int d = j*16 + l15;
                short4 vv;
                vv.x = f2bf(acc[i][j][0]);
                vv.y = f2bf(acc[i][j][1]);
                vv.z = f2bf(acc[i][j][2]);
                vv.w = f2bf(acc[i][j][3]);
                *(short4*)(Vtb + ((size_t)bh*D_ + d)*N_ + n0) = vv;
            }
        }
    }
}

// ---------------------------------------------------------------------------
// Flash attention, 32x32x16 bf16 MFMA, no-max softmax, split-K over grid.z.
// LDS-BW-BOUND FIX (R8 post-mortem): K fragments are loaded DIRECTLY from
// global (S^T A-operand is 16 contiguous bytes/lane: row k = kt*32+l31,
// chunk kc*16+hi*8) — K never touches LDS. Only V^T (transpose required)
// is staged, double-buffered at zero residency cost (LDS 16 KB total; Q
// staged into Vts[0] pre-loop). DS traffic/block-iter: 48 KB (R6) -> 24 KB.
// One barrier per iter: top-of-loop sync drains prev V-prefetch + fences
// both waves' reads before overwrite; prefetch flies over current compute.
// S^T trick: mfma(K,Q) puts q = lane&31 (A-operand mapping for PV); P
// transposed in-register via 4 shfl_xor(32) per kt; trunc-packed bf16;
// l from ones-MFMA on the same truncated P frags (ratio-consistent).
// LDS rows 128B, XOR-swizzled: chunk c of row r lives at (c ^ (r&7))*16B.
// 32x32 C layout: col = lane&31, row = (reg&3) + 8*(reg>>2) + 4*(lane>>5).
// NO min-wave launch bound (R7: capping below the 48-AGPR live-range spills).
// Grid: (q-tiles, bh, split) so consecutive blocks share K/V in L2.
// ---------------------------------------------------------------------------
__global__ __launch_bounds__(128) void attn_mfma(const short* __restrict__ Qb,
                                                 const short* __restrict__ Kb,
                                                 const short* __restrict__ Vtb,
                                                 float* __restrict__ Opart,
                                                 float* __restrict__ lpart) {
    __shared__ short Vts[2][64*64];   // [d][k]; Vts[0] doubles as Q staging
    const int t = threadIdx.x;
    const int w = t >> 6, lane = t & 63;
    const int l31 = lane & 31, hi = lane >> 5;
    const int q0 = blockIdx.x * 64, bh = blockIdx.y;
    const int split = blockIdx.z;
    const int kbase = split * KSPAN;
    const size_t base = (size_t)bh * N_ * D_;
    const int lrow = lane >> 3;            // row within 8-row segment
    const int lc   = (lane & 7) ^ lrow;    // swizzled source chunk

    // stage Q tile (64 x 64) into Vts[0], swizzled
    #pragma unroll
    for (int r = 0; r < 4; ++r) {
        int s = r*2 + w;
        int row = s*8 + lrow;
        gl2lds16(Qb + base + (size_t)(q0+row)*D_ + lc*8, Vts[0] + s*512);
    }
    __syncthreads();

    // hoist Q B-frags (loop-invariant)
    bfrag qf[4];
    {
        int row = w*32 + l31, r7 = row & 7;
        #pragma unroll
        for (int kc = 0; kc < 4; ++kc)
            qf[kc] = *(const bfrag*)(Vts[0] + row*64 + ((kc*2 + hi) ^ r7)*8);
    }
    __syncthreads();   // both waves' hoists done; Vts[0] now writable

    // stage V k-tile 0 into Vts[0]
    #pragma unroll
    for (int r = 0; r < 4; ++r) {
        int s = r*2 + w;
        int row = s*8 + lrow;
        gl2lds16(Vtb + (size_t)(bh*D_ + row)*N_ + kbase + lc*8, Vts[0] + s*512);
    }

    // ones B-frag for the l (row-sum) MFMA
    bfrag vones;
    #pragma unroll
    for (int j = 0; j < 8; ++j) vones[j] = (short)0x3f80;

    ffrag16 oacc[2], lfr;
    #pragma unroll
    for (int r = 0; r < 16; ++r) { oacc[0][r] = 0.f; oacc[1][r] = 0.f; lfr[r] = 0.f; }

    const int nIters = KSPAN / 64;         // 18
    for (int it = 0; it < nIters; ++it) {
        const int cur = it & 1, nxt = cur ^ 1;
        const int k0  = kbase + it * 64;

        // (a) drains V-stage for cur; (b) fences both waves' nxt reads
        __syncthreads();

        // prefetch next V tile into the other buffer
        if (it + 1 < nIters) {
            int k1 = k0 + 64;
            #pragma unroll
            for (int r = 0; r < 4; ++r) {
                int s = r*2 + w;
                int row = s*8 + lrow;
                gl2lds16(Vtb + (size_t)(bh*D_ + row)*N_ + k1 + lc*8, Vts[nxt] + s*512);
            }
        }

        // ---- compute: QK^T with K frags direct from global ----
        ufrag pfr[4];                      // A-frags for PV, kc = kt*2 + {lo,hi}
        #pragma unroll
        for (int kt = 0; kt < 2; ++kt) {
            const short* kp = Kb + base + (size_t)(k0 + kt*32 + l31)*D_ + hi*8;
            bfrag kf0 = *(const bfrag*)(kp);
            bfrag kf1 = *(const bfrag*)(kp + 16);
            bfrag kf2 = *(const bfrag*)(kp + 32);
            bfrag kf3 = *(const bfrag*)(kp + 48);
            ffrag16 s;
            #pragma unroll
            for (int r = 0; r < 16; ++r) s[r] = 0.f;
            s = __builtin_amdgcn_mfma_f32_32x32x16_bf16(kf0, qf[0], s, 0, 0, 0);
            s = __builtin_amdgcn_mfma_f32_32x32x16_bf16(kf1, qf[1], s, 0, 0, 0);
            s = __builtin_amdgcn_mfma_f32_32x32x16_bf16(kf2, qf[2], s, 0, 0, 0);
            s = __builtin_amdgcn_mfma_f32_32x32x16_bf16(kf3, qf[3], s, 0, 0, 0);
            #pragma unroll
            for (int r = 0; r < 16; ++r)
                s[r] = __builtin_amdgcn_exp2f(s[r]);
            // group g (regs 4g..4g+3) holds k_local = 8g + 4hi + {0..3}
            unsigned q01_0 = pktrunc(s[0],  s[1]),  q23_0 = pktrunc(s[2],  s[3]);
            unsigned q01_1 = pktrunc(s[4],  s[5]),  q23_1 = pktrunc(s[6],  s[7]);
            unsigned q01_2 = pktrunc(s[8],  s[9]),  q23_2 = pktrunc(s[10], s[11]);
            unsigned q01_3 = pktrunc(s[12], s[13]), q23_3 = pktrunc(s[14], s[15]);
            // exchange the half each partner needs (partner has hi^1)
            unsigned r0 = __shfl_xor(hi ? q01_0 : q01_1, 32, 64);
            unsigned r1 = __shfl_xor(hi ? q23_0 : q23_1, 32, 64);
            unsigned r2 = __shfl_xor(hi ? q01_2 : q01_3, 32, 64);
            unsigned r3 = __shfl_xor(hi ? q23_2 : q23_3, 32, 64);
            ufrag lo, hif;
            lo[0] = hi ? r0 : q01_0;  lo[1] = hi ? r1 : q23_0;
            lo[2] = hi ? q01_1 : r0;  lo[3] = hi ? q23_1 : r1;
            hif[0] = hi ? r2 : q01_2; hif[1] = hi ? r3 : q23_2;
            hif[2] = hi ? q01_3 : r2; hif[3] = hi ? q23_3 : r3;
            pfr[kt*2]     = lo;        // k_local 0-15
            pfr[kt*2 + 1] = hif;       // k_local 16-31
        }

        // O += P V ; l += P 1  (same truncated P frags; V from LDS[cur])
        #pragma unroll
        for (int kc = 0; kc < 4; ++kc) {
            bfrag pf = __builtin_bit_cast(bfrag, pfr[kc]);
            #pragma unroll
            for (int dt = 0; dt < 2; ++dt) {
                int row = dt*32 + l31, r7 = row & 7;
                bfrag vf = *(const bfrag*)(Vts[cur] + row*64 + ((kc*2 + hi) ^ r7)*8);
                oacc[dt] = __builtin_amdgcn_mfma_f32_32x32x16_bf16(pf, vf, oacc[dt], 0, 0, 0);
            }
            lfr = __builtin_amdgcn_mfma_f32_32x32x16_bf16(pf, vones, lfr, 0, 0, 0);
        }
    }

    const int b = bh / HEADS, head = bh - b*HEADS;
    float* Op = Opart + (size_t)split * M_ * C_;
    float* lp = lpart + (size_t)split * (B_*HEADS) * N_;

    // lfr: every column (lane) holds l[q-row]; rows mapped like oacc
    if (l31 == 0) {
        #pragma unroll
        for (int r = 0; r < 16; ++r) {
            int n = q0 + w*32 + (r & 3) + 8*(r >> 2) + 4*hi;
            lp[bh*N_ + n] = lfr[r];
        }
    }

    #pragma unroll
    for (int dt = 0; dt < 2; ++dt)
        #pragma unroll
        for (int r = 0; r < 16; ++r) {
            int n = q0 + w*32 + (r & 3) + 8*(r >> 2) + 4*hi;
            int c = head*D_ + dt*32 + l31;
            Op[((size_t)b*N_ + n)*C_ + c] = oacc[dt][r];
        }
}

// ---------------------------------------------------------------------------
// Merge split-K partials: Ob = (sum_s O_s) / (sum_s l_s), bf16 out.
// ---------------------------------------------------------------------------
__global__ __launch_bounds__(256) void attn_merge(const float* __restrict__ Opart,
                                                  const float* __restrict__ lpart,
                                                  short* __restrict__ Ob) {
    int i = blockIdx.x * 256 + threadIdx.x;          // over M_*C_/4
    int m = i / (C_/4);
    int c = (i - m*(C_/4)) * 4;
    int b = m / N_, n = m - b*N_;
    int bh = b*HEADS + (c >> 6);
    float4 o0 = ((const float4*)Opart)[i];
    float4 o1 = ((const float4*)(Opart + (size_t)M_*C_))[i];
    float l = lpart[bh*N_ + n] + lpart[(B_*HEADS)*N_ + bh*N_ + n];
    float inv = 1.f / l;
    short4 o;
    o.x = f2bf((o0.x + o1.x) * inv);
    o.y = f2bf((o0.y + o1.y) * inv);
    o.z = f2bf((o0.z + o1.z) * inv);
    o.w = f2bf((o0.w + o1.w) * inv);
    ((short4*)Ob)[i] = o;
}

// ---------------------------------------------------------------------------
// Proj GEMM: out[m][f] = sum_c O[m][c]*w[f][c] + bias[f], fp32 out.
// BK=32 (R7 config — BK=64 proj regressed ~3.5 us in R8).
// ---------------------------------------------------------------------------
__global__ __launch_bounds__(256) void proj_gemm(const short* __restrict__ Ab,
                                                 const short* __restrict__ wb,
                                                 const float* __restrict__ bias,
                                                 float* __restrict__ out) {
    __shared__ short As[128*32];
    __shared__ short Bs[128*32];
    const int t = threadIdx.x;
    const int w = t >> 6, lane = t & 63;
    const int quad = lane >> 4, l15 = lane & 15;
    const int wr = w >> 1, wc = w & 1;
    const int m0 = blockIdx.y * 128, f0 = blockIdx.x * 128;

    ffrag acc[4][4] = {};

    for (int k0 = 0; k0 < C_; k0 += 32) {
        __syncthreads();
        #pragma unroll
        for (int r = 0; r < 2; ++r) {
            int seg = r*4 + w;
            int row = seg*16 + (lane >> 2);
            int kk  = (lane & 3) * 8;
            gl2lds16(Ab + (size_t)(m0+row)*C_ + k0 + kk, As + seg*512);
            gl2lds16(wb + (size_t)(f0+row)*C_ + k0 + kk, Bs + seg*512);
        }
        __syncthreads();
        bfrag af[4], bf[4];
        #pragma unroll
        for (int i = 0; i < 4; ++i)
            af[i] = *(const bfrag*)(As + (wr*64 + i*16 + l15)*32 + quad*8);
        #pragma unroll
        for (int j = 0; j < 4; ++j)
            bf[j] = *(const bfrag*)(Bs + (wc*64 + j*16 + l15)*32 + quad*8);
        #pragma unroll
        for (int i = 0; i < 4; ++i)
            #pragma unroll
            for (int j = 0; j < 4; ++j)
                acc[i][j] = __builtin_amdgcn_mfma_f32_16x16x32_bf16(af[i], bf[j], acc[i][j], 0, 0, 0);
    }

    #pragma unroll
    for (int i = 0; i < 4; ++i) {
        int mbase = m0 + wr*64 + i*16 + quad*4;
        #pragma unroll
        for (int j = 0; j < 4; ++j) {
            int f = f0 + wc*64 + j*16 + l15;
            float bv = bias[f];
            #pragma unroll
            for (int r = 0; r < 4; ++r)
                out[(size_t)(mbase + r)*C_ + f] = acc[i][j][r] + bv;
        }
    }
}

// ---------------------------------------------------------------------------
extern "C" void kernel_launch(void* const* d_in, const int* in_sizes, int n_in,
                              void* d_out, int out_size, void* d_ws, size_t ws_size,
                              hipStream_t stream) {
    const float* x      = (const float*)d_in[0];
    const float* qkv_w  = (const float*)d_in[3];
    const float* proj_w = (const float*)d_in[4];
    const float* proj_b = (const float*)d_in[5];
    float* out = (float*)d_out;

    const size_t nx = (size_t)M_ * C_;        // 3,538,944
    const size_t nq = (size_t)F3 * C_;        // 1,769,472
    const size_t np = (size_t)C_ * C_;        //   589,824
    short* xb  = (short*)d_ws;
    short* qwb = xb  + nx;
    short* pwb = qwb + nq;
    short* Qb  = pwb + np;
    short* Kb  = Qb  + nx;
    short* Vtb = Kb  + nx;
    short* Ob  = Vtb + nx;
    float* Opart = (float*)(Ob + nx);                       // SPLITS * M_*C_
    float* lpart = Opart + (size_t)SPLITS * M_ * C_;        // SPLITS * 24*N_

    const int ncast4 = (int)((nx + nq + np) / 4);
    cast_all<<<dim3((ncast4 + 255)/256), 256, 0, stream>>>(x, qkv_w, proj_w, xb);

    qkv_gemm<<<dim3(F3/128, M_/128), 256, 0, stream>>>(xb, qwb, Qb, Kb, Vtb);
    attn_mfma<<<dim3(N_/64, B_*HEADS, SPLITS), 128, 0, stream>>>(Qb, Kb, Vtb, Opart, lpart);
    attn_merge<<<dim3(((int)(nx/4) + 255)/256), 256, 0, stream>>>(Opart, lpart, Ob);
    proj_gemm<<<dim3(C_/128, M_/128), 256, 0, stream>>>(Ob, pwb, proj_b, out);
}

// Round 10
// 211.184 us; speedup vs baseline: 1.1418x; 1.1418x over previous
//
#include <hip/hip_runtime.h>

#define B_    2
#define N_    2304
#define C_    768
#define HEADS 12
#define D_    64
#define F3    2304
#define M_    (B_*N_)        // 4608
#define SPLITS 2
#define KSPAN (N_/SPLITS)    // 1152
// SCALE(0.125) * log2(e) folded into Q at qkv epilogue:
#define QSCALE 0.18033688011112042f

typedef __attribute__((ext_vector_type(8)))  short bfrag;    // 8 x bf16 (4 VGPR)
typedef __attribute__((ext_vector_type(4)))  float ffrag;    // 16x16 acc
typedef __attribute__((ext_vector_type(16))) float ffrag16;  // 32x32 acc
typedef __attribute__((ext_vector_type(4)))  unsigned ufrag; // 4 x b32 = 8 bf16

__device__ __forceinline__ short f2bf(float f) {
    unsigned u = __float_as_uint(f);
    u += 0x7fff + ((u >> 16) & 1);          // RNE
    return (short)(u >> 16);
}

__device__ __forceinline__ void gl2lds16(const void* g, void* l) {
    __builtin_amdgcn_global_load_lds(
        (const __attribute__((address_space(1))) void*)g,
        (__attribute__((address_space(3))) void*)l, 16, 0, 0);
}

// trunc-pack two fp32 -> (bf16(a) low | bf16(b) high) in ONE v_perm_b32.
// bias-safe: numerator (PV) and denominator (ones-MFMA) consume the same
// truncated fragments -> common bias cancels in the ratio.
__device__ __forceinline__ unsigned pktrunc(float a, float b) {
    return __builtin_amdgcn_perm(__float_as_uint(a), __float_as_uint(b),
                                 0x03020706u);
}

// ---------------------------------------------------------------------------
// Fused fp32 -> bf16 cast of x, qkv_w, proj_w (dsts contiguous in ws).
// ---------------------------------------------------------------------------
__global__ __launch_bounds__(256) void cast_all(const float* __restrict__ x,
                                                const float* __restrict__ qw,
                                                const float* __restrict__ pw,
                                                short* __restrict__ dst) {
    const int nx4 = (M_*C_)/4, nq4 = (F3*C_)/4, np4 = (C_*C_)/4;
    int i = blockIdx.x * 256 + threadIdx.x;
    if (i >= nx4 + nq4 + np4) return;
    const float* src; int off;
    if (i < nx4)            { src = x;  off = i; }
    else if (i < nx4 + nq4) { src = qw; off = i - nx4; }
    else                    { src = pw; off = i - nx4 - nq4; }
    float4 v = ((const float4*)src)[off];
    short4 o;
    o.x = f2bf(v.x); o.y = f2bf(v.y); o.z = f2bf(v.z); o.w = f2bf(v.w);
    ((short4*)dst)[i] = o;
}

// ---------------------------------------------------------------------------
// QKV GEMM: qkv[m][f] = sum_c x[m][c]*w[f][c]  (NT).  BK=64, XOR-swizzled
// staging (slot = chunk ^ (row&7)); 12 k-iters, 32 MFMA/iter.
// Q stored pre-scaled by SCALE*log2e; V stored transposed [bh,d,n].
// ---------------------------------------------------------------------------
__global__ __launch_bounds__(256) void qkv_gemm(const short* __restrict__ xb,
                                                const short* __restrict__ wb,
                                                short* __restrict__ Qb,
                                                short* __restrict__ Kb,
                                                short* __restrict__ Vtb) {
    __shared__ short As[128*64];
    __shared__ short Bs[128*64];
    const int t = threadIdx.x;
    const int w = t >> 6, lane = t & 63;
    const int quad = lane >> 4, l15 = lane & 15;
    const int wr = w >> 1, wc = w & 1;
    const int m0 = blockIdx.y * 128, f0 = blockIdx.x * 128;
    const int lrow = lane >> 3;            // row within 8-row segment
    const int lc   = (lane & 7) ^ lrow;    // swizzled source chunk
    const int r7   = l15 & 7;              // frag-row swizzle key

    ffrag acc[4][4] = {};

    for (int k0 = 0; k0 < C_; k0 += 64) {
        __syncthreads();
        #pragma unroll
        for (int r = 0; r < 4; ++r) {
            int seg = r*4 + w;                 // 16 segments of 8 rows
            int row = seg*8 + lrow;
            gl2lds16(xb + (size_t)(m0+row)*C_ + k0 + lc*8, As + seg*512);
            gl2lds16(wb + (size_t)(f0+row)*C_ + k0 + lc*8, Bs + seg*512);
        }
        __syncthreads();
        #pragma unroll
        for (int s = 0; s < 2; ++s) {
            bfrag af[4], bf[4];
            int slot = (s*4 + quad) ^ r7;
            #pragma unroll
            for (int i = 0; i < 4; ++i)
                af[i] = *(const bfrag*)(As + (wr*64 + i*16 + l15)*64 + slot*8);
            #pragma unroll
            for (int j = 0; j < 4; ++j)
                bf[j] = *(const bfrag*)(Bs + (wc*64 + j*16 + l15)*64 + slot*8);
            #pragma unroll
            for (int i = 0; i < 4; ++i)
                #pragma unroll
                for (int j = 0; j < 4; ++j)
                    acc[i][j] = __builtin_amdgcn_mfma_f32_16x16x32_bf16(af[i], bf[j], acc[i][j], 0, 0, 0);
        }
    }

    const int b   = m0 / N_;
    const int seg = f0 + wc*64;
    const int which = seg / C_;                  // 0=Q 1=K 2=V
    const int head  = (seg - which*C_) >> 6;
    const int bh    = b*HEADS + head;
    const int nbase = (m0 - b*N_) + wr*64 + quad*4;

    if (which == 0) {
        #pragma unroll
        for (int i = 0; i < 4; ++i) {
            int n0 = nbase + i*16;
            #pragma unroll
            for (int j = 0; j < 4; ++j) {
                int d = j*16 + l15;
                #pragma unroll
                for (int r = 0; r < 4; ++r)
                    Qb[((size_t)bh*N_ + n0 + r)*D_ + d] = f2bf(acc[i][j][r] * QSCALE);
            }
        }
    } else if (which == 1) {
        #pragma unroll
        for (int i = 0; i < 4; ++i) {
            int n0 = nbase + i*16;
            #pragma unroll
            for (int j = 0; j < 4; ++j) {
                int d = j*16 + l15;
                #pragma unroll
                for (int r = 0; r < 4; ++r)
                    Kb[((size_t)bh*N_ + n0 + r)*D_ + d] = f2bf(acc[i][j][r]);
            }
        }
    } else {
        #pragma unroll
        for (int i = 0; i < 4; ++i) {
            int n0 = nbase + i*16;
            #pragma unroll
            for (int j = 0; j < 4; ++j) {
                int d = j*16 + l15;
                short4 vv;
                vv.x = f2bf(acc[i][j][0]);
                vv.y = f2bf(acc[i][j][1]);
                vv.z = f2bf(acc[i][j][2]);
                vv.w = f2bf(acc[i][j][3]);
                *(short4*)(Vtb + ((size_t)bh*D_ + d)*N_ + n0) = vv;
            }
        }
    }
}

// ---------------------------------------------------------------------------
// Flash attention, 32x32x16 bf16 MFMA, no-max softmax, split-K over grid.z.
// R6 compute body (best measured: 67 us) with ONE change: Q is staged
// through Ks (dead after the register hoist), shrinking LDS 24.5 -> 16 KB
// so all ~6.75 dispatched blocks/CU can be co-resident (R6 showed ~2.3
// effective).  K and V^T both staged per k-iter, 2 barriers/iter — the
// R8 dbuf (32 KB) and R9 global-direct-K (FETCH 12->61 MB) both regressed.
// S^T trick: mfma(K,Q) puts q = lane&31 (A-operand mapping for PV); P
// transposed in-register via 4 shfl_xor(32) per kt; trunc-packed bf16;
// l from ones-MFMA on the same truncated P frags (ratio-consistent).
// LDS rows 128B, XOR-swizzled: chunk c of row r lives at (c ^ (r&7))*16B.
// 32x32 C layout: col = lane&31, row = (reg&3) + 8*(reg>>2) + 4*(lane>>5).
// NO min-wave launch bound (R7: capping below the 48-AGPR live-range spills).
// ---------------------------------------------------------------------------
__global__ __launch_bounds__(128) void attn_mfma(const short* __restrict__ Qb,
                                                 const short* __restrict__ Kb,
                                                 const short* __restrict__ Vtb,
                                                 float* __restrict__ Opart,
                                                 float* __restrict__ lpart) {
    __shared__ short Ks[64*64];
    __shared__ short Vts[64*64];   // [d][k]
    const int t = threadIdx.x;
    const int w = t >> 6, lane = t & 63;
    const int l31 = lane & 31, hi = lane >> 5;
    const int bh = blockIdx.x, q0 = blockIdx.y * 64;
    const int split = blockIdx.z;
    const int kbase = split * KSPAN;
    const size_t base = (size_t)bh * N_ * D_;
    const int lrow = lane >> 3;            // row within 8-row segment
    const int lc   = (lane & 7) ^ lrow;    // swizzled source chunk

    // stage Q tile (64 x 64) into Ks (dead after hoist), swizzled
    #pragma unroll
    for (int r = 0; r < 4; ++r) {
        int s = r*2 + w;
        int row = s*8 + lrow;
        gl2lds16(Qb + base + (size_t)(q0+row)*D_ + lc*8, Ks + s*512);
    }
    __syncthreads();

    // hoist Q B-frags (loop-invariant)
    bfrag qf[4];
    {
        int row = w*32 + l31, r7 = row & 7;
        #pragma unroll
        for (int kc = 0; kc < 4; ++kc)
            qf[kc] = *(const bfrag*)(Ks + row*64 + ((kc*2 + hi) ^ r7)*8);
    }

    // ones B-frag for the l (row-sum) MFMA
    bfrag vones;
    #pragma unroll
    for (int j = 0; j < 8; ++j) vones[j] = (short)0x3f80;

    ffrag16 oacc[2], lfr;
    #pragma unroll
    for (int r = 0; r < 16; ++r) { oacc[0][r] = 0.f; oacc[1][r] = 0.f; lfr[r] = 0.f; }

    for (int k0 = kbase; k0 < kbase + KSPAN; k0 += 64) {
        __syncthreads();                   // prev iter frag reads done (also Q hoist)
        #pragma unroll
        for (int r = 0; r < 4; ++r) {
            int s = r*2 + w;
            int row = s*8 + lrow;
            gl2lds16(Kb  + base + (size_t)(k0+row)*D_ + lc*8,    Ks  + s*512);
            gl2lds16(Vtb + (size_t)(bh*D_ + row)*N_ + k0 + lc*8, Vts + s*512);
        }
        __syncthreads();                   // staging visible

        ufrag pfr[4];                      // A-frags for PV, kc = kt*2 + {lo,hi}
        #pragma unroll
        for (int kt = 0; kt < 2; ++kt) {
            ffrag16 s;
            #pragma unroll
            for (int r = 0; r < 16; ++r) s[r] = 0.f;
            int row = kt*32 + l31, r7 = row & 7;
            #pragma unroll
            for (int kc = 0; kc < 4; ++kc) {
                bfrag kf = *(const bfrag*)(Ks + row*64 + ((kc*2 + hi) ^ r7)*8);
                s = __builtin_amdgcn_mfma_f32_32x32x16_bf16(kf, qf[kc], s, 0, 0, 0);
            }
            #pragma unroll
            for (int r = 0; r < 16; ++r)
                s[r] = __builtin_amdgcn_exp2f(s[r]);
            // group g (regs 4g..4g+3) holds k_local = 8g + 4hi + {0..3}
            unsigned q01_0 = pktrunc(s[0],  s[1]),  q23_0 = pktrunc(s[2],  s[3]);
            unsigned q01_1 = pktrunc(s[4],  s[5]),  q23_1 = pktrunc(s[6],  s[7]);
            unsigned q01_2 = pktrunc(s[8],  s[9]),  q23_2 = pktrunc(s[10], s[11]);
            unsigned q01_3 = pktrunc(s[12], s[13]), q23_3 = pktrunc(s[14], s[15]);
            // exchange the half each partner needs (partner has hi^1)
            unsigned r0 = __shfl_xor(hi ? q01_0 : q01_1, 32, 64);
            unsigned r1 = __shfl_xor(hi ? q23_0 : q23_1, 32, 64);
            unsigned r2 = __shfl_xor(hi ? q01_2 : q01_3, 32, 64);
            unsigned r3 = __shfl_xor(hi ? q23_2 : q23_3, 32, 64);
            ufrag lo, hif;
            lo[0] = hi ? r0 : q01_0;  lo[1] = hi ? r1 : q23_0;
            lo[2] = hi ? q01_1 : r0;  lo[3] = hi ? q23_1 : r1;
            hif[0] = hi ? r2 : q01_2; hif[1] = hi ? r3 : q23_2;
            hif[2] = hi ? q01_3 : r2; hif[3] = hi ? q23_3 : r3;
            pfr[kt*2]     = lo;        // k_local 0-15
            pfr[kt*2 + 1] = hif;       // k_local 16-31
        }

        // O += P V ; l += P 1  (same truncated P frags)
        #pragma unroll
        for (int kc = 0; kc < 4; ++kc) {
            bfrag pf = __builtin_bit_cast(bfrag, pfr[kc]);
            #pragma unroll
            for (int dt = 0; dt < 2; ++dt) {
                int row = dt*32 + l31, r7 = row & 7;
                bfrag vf = *(const bfrag*)(Vts + row*64 + ((kc*2 + hi) ^ r7)*8);
                oacc[dt] = __builtin_amdgcn_mfma_f32_32x32x16_bf16(pf, vf, oacc[dt], 0, 0, 0);
            }
            lfr = __builtin_amdgcn_mfma_f32_32x32x16_bf16(pf, vones, lfr, 0, 0, 0);
        }
    }

    const int b = bh / HEADS, head = bh - b*HEADS;
    float* Op = Opart + (size_t)split * M_ * C_;
    float* lp = lpart + (size_t)split * (B_*HEADS) * N_;

    // lfr: every column (lane) holds l[q-row]; rows mapped like oacc
    if (l31 == 0) {
        #pragma unroll
        for (int r = 0; r < 16; ++r) {
            int n = q0 + w*32 + (r & 3) + 8*(r >> 2) + 4*hi;
            lp[bh*N_ + n] = lfr[r];
        }
    }

    #pragma unroll
    for (int dt = 0; dt < 2; ++dt)
        #pragma unroll
        for (int r = 0; r < 16; ++r) {
            int n = q0 + w*32 + (r & 3) + 8*(r >> 2) + 4*hi;
            int c = head*D_ + dt*32 + l31;
            Op[((size_t)b*N_ + n)*C_ + c] = oacc[dt][r];
        }
}

// ---------------------------------------------------------------------------
// Merge split-K partials: Ob = (sum_s O_s) / (sum_s l_s), bf16 out.
// ---------------------------------------------------------------------------
__global__ __launch_bounds__(256) void attn_merge(const float* __restrict__ Opart,
                                                  const float* __restrict__ lpart,
                                                  short* __restrict__ Ob) {
    int i = blockIdx.x * 256 + threadIdx.x;          // over M_*C_/4
    int m = i / (C_/4);
    int c = (i - m*(C_/4)) * 4;
    int b = m / N_, n = m - b*N_;
    int bh = b*HEADS + (c >> 6);
    float4 o0 = ((const float4*)Opart)[i];
    float4 o1 = ((const float4*)(Opart + (size_t)M_*C_))[i];
    float l = lpart[bh*N_ + n] + lpart[(B_*HEADS)*N_ + bh*N_ + n];
    float inv = 1.f / l;
    short4 o;
    o.x = f2bf((o0.x + o1.x) * inv);
    o.y = f2bf((o0.y + o1.y) * inv);
    o.z = f2bf((o0.z + o1.z) * inv);
    o.w = f2bf((o0.w + o1.w) * inv);
    ((short4*)Ob)[i] = o;
}

// ---------------------------------------------------------------------------
// Proj GEMM: out[m][f] = sum_c O[m][c]*w[f][c] + bias[f], fp32 out.
// BK=32 (BK=64 proj regressed ~3.5 us in R8).
// ---------------------------------------------------------------------------
__global__ __launch_bounds__(256) void proj_gemm(const short* __restrict__ Ab,
                                                 const short* __restrict__ wb,
                                                 const float* __restrict__ bias,
                                                 float* __restrict__ out) {
    __shared__ short As[128*32];
    __shared__ short Bs[128*32];
    const int t = threadIdx.x;
    const int w = t >> 6, lane = t & 63;
    const int quad = lane >> 4, l15 = lane & 15;
    const int wr = w >> 1, wc = w & 1;
    const int m0 = blockIdx.y * 128, f0 = blockIdx.x * 128;

    ffrag acc[4][4] = {};

    for (int k0 = 0; k0 < C_; k0 += 32) {
        __syncthreads();
        #pragma unroll
        for (int r = 0; r < 2; ++r) {
            int seg = r*4 + w;
            int row = seg*16 + (lane >> 2);
            int kk  = (lane & 3) * 8;
            gl2lds16(Ab + (size_t)(m0+row)*C_ + k0 + kk, As + seg*512);
            gl2lds16(wb + (size_t)(f0+row)*C_ + k0 + kk, Bs + seg*512);
        }
        __syncthreads();
        bfrag af[4], bf[4];
        #pragma unroll
        for (int i = 0; i < 4; ++i)
            af[i] = *(const bfrag*)(As + (wr*64 + i*16 + l15)*32 + quad*8);
        #pragma unroll
        for (int j = 0; j < 4; ++j)
            bf[j] = *(const bfrag*)(Bs + (wc*64 + j*16 + l15)*32 + quad*8);
        #pragma unroll
        for (int i = 0; i < 4; ++i)
            #pragma unroll
            for (int j = 0; j < 4; ++j)
                acc[i][j] = __builtin_amdgcn_mfma_f32_16x16x32_bf16(af[i], bf[j], acc[i][j], 0, 0, 0);
    }

    #pragma unroll
    for (int i = 0; i < 4; ++i) {
        int mbase = m0 + wr*64 + i*16 + quad*4;
        #pragma unroll
        for (int j = 0; j < 4; ++j) {
            int f = f0 + wc*64 + j*16 + l15;
            float bv = bias[f];
            #pragma unroll
            for (int r = 0; r < 4; ++r)
                out[(size_t)(mbase + r)*C_ + f] = acc[i][j][r] + bv;
        }
    }
}

// ---------------------------------------------------------------------------
extern "C" void kernel_launch(void* const* d_in, const int* in_sizes, int n_in,
                              void* d_out, int out_size, void* d_ws, size_t ws_size,
                              hipStream_t stream) {
    const float* x      = (const float*)d_in[0];
    const float* qkv_w  = (const float*)d_in[3];
    const float* proj_w = (const float*)d_in[4];
    const float* proj_b = (const float*)d_in[5];
    float* out = (float*)d_out;

    const size_t nx = (size_t)M_ * C_;        // 3,538,944
    const size_t nq = (size_t)F3 * C_;        // 1,769,472
    const size_t np = (size_t)C_ * C_;        //   589,824
    short* xb  = (short*)d_ws;
    short* qwb = xb  + nx;
    short* pwb = qwb + nq;
    short* Qb  = pwb + np;
    short* Kb  = Qb  + nx;
    short* Vtb = Kb  + nx;
    short* Ob  = Vtb + nx;
    float* Opart = (float*)(Ob + nx);                       // SPLITS * M_*C_
    float* lpart = Opart + (size_t)SPLITS * M_ * C_;        // SPLITS * 24*N_

    const int ncast4 = (int)((nx + nq + np) / 4);
    cast_all<<<dim3((ncast4 + 255)/256), 256, 0, stream>>>(x, qkv_w, proj_w, xb);

    qkv_gemm<<<dim3(F3/128, M_/128), 256, 0, stream>>>(xb, qwb, Qb, Kb, Vtb);
    attn_mfma<<<dim3(B_*HEADS, N_/64, SPLITS), 128, 0, stream>>>(Qb, Kb, Vtb, Opart, lpart);
    attn_merge<<<dim3(((int)(nx/4) + 255)/256), 256, 0, stream>>>(Opart, lpart, Ob);
    proj_gemm<<<dim3(C_/128, M_/128), 256, 0, stream>>>(Ob, pwb, proj_b, out);
}